// Round 7
// baseline (149.097 us; speedup 1.0000x reference)
//
#include <hip/hip_runtime.h>
#include <math.h>

#define BS 8
#define NQ 1024
#define NT 128                 // targets per batch (solver rows)
#define MCOLS 1024             // solver columns = NQ (transposed problem)
#define TT 1024                // total targets = BS*NT
#define CM_ELEMS (BS * NQ * TT)
#define NSOLVE 8               // solver blocks (one per batch)
#define NCOST 248              // cost blocks; NSOLVE+NCOST = 256 = #CUs
                               // -> bijective block->CU map, zero CU sharing

typedef float v2f __attribute__((ext_vector_type(2)));

__device__ __forceinline__ float sigmoidf_(float x) {
    return 1.0f / (1.0f + expf(-x));
}

// Full cost (cost path). Strict sequential order, contraction off.
// Validated bit-compatible with the JAX reference in rounds 2-6.
__device__ __forceinline__ float cost_fn(float prob, float4 qb, float qa,
                                         float4 tb, float ta, float tl) {
#pragma clang fp contract(off)
    float cl = -(prob * tl);
    float ca = fabsf(qa - ta);
    float s01 = fabsf(qb.x - tb.x) + fabsf(qb.y - tb.y);
    float s012 = s01 + fabsf(qb.z - tb.z);
    float cb = s012 + fabsf(qb.w - tb.w);
    return (2.0f * cl + ca) + 5.0f * cb;
}

union DU { double d; int2 i; };

#define DPP_FMIN(CTRL, RMASK)                                                  \
    do {                                                                       \
        DU cv_; cv_.d = mval;                                                  \
        int lo_ = __builtin_amdgcn_update_dpp(cv_.i.x, cv_.i.x, (CTRL), (RMASK), 0xF, false); \
        int hi_ = __builtin_amdgcn_update_dpp(cv_.i.y, cv_.i.y, (CTRL), (RMASK), 0xF, false); \
        DU ov_; ov_.i.x = lo_; ov_.i.y = hi_;                                  \
        mval = fmin(mval, ov_.d);                                              \
    } while (0)

// ---------------- Fused kernel --------------------------------------------
// blocks 0..7: solver (setprio 3 protects the serial latency chain);
// blocks 8..255: cost matrix, grid-stride over the 8192 queries (33-34 each),
// hidden under the solver's ~120+ us runtime. 256 blocks == 256 CUs.
__global__ void __launch_bounds__(256) fused_kernel(
    const float* __restrict__ logits, const float* __restrict__ boxes,
    const float* __restrict__ angle,  const float* __restrict__ tboxes,
    const float* __restrict__ tangle, const float* __restrict__ tlabels,
    float* __restrict__ out) {
    const int tid = threadIdx.x;

    __shared__ double u_col[MCOLS + 1];      // u of the row assigned to col j
    __shared__ float4 tb_col[MCOLS + 1];     // target box of that row
    __shared__ float  ta_col[MCOLS + 1];     // target angle of that row
    __shared__ int    p_col[MCOLS + 1];      // assigned row (0 = none)
    __shared__ float  s_ta[NT];
    __shared__ float4 s_tb[NT];
    __shared__ int4   s_comb[2][4];          // parity-buffered wave partials
    __shared__ int    s_wsum[4];

    if (blockIdx.x >= NSOLVE) {
        // ---------------- cost-matrix path ----------------
        const int t0 = tid * 4;
        const float4 tb0 = reinterpret_cast<const float4*>(tboxes)[t0 + 0];
        const float4 tb1 = reinterpret_cast<const float4*>(tboxes)[t0 + 1];
        const float4 tb2 = reinterpret_cast<const float4*>(tboxes)[t0 + 2];
        const float4 tb3 = reinterpret_cast<const float4*>(tboxes)[t0 + 3];
        const float ta0 = tangle[t0 + 0], ta1 = tangle[t0 + 1];
        const float ta2 = tangle[t0 + 2], ta3 = tangle[t0 + 3];
        const float tl0 = tlabels[t0 + 0], tl1 = tlabels[t0 + 1];
        const float tl2 = tlabels[t0 + 2], tl3 = tlabels[t0 + 3];

        for (int bq = blockIdx.x - NSOLVE; bq < BS * NQ; bq += NCOST) {
            const float prob = sigmoidf_(logits[bq]);
            const float4 qbv = reinterpret_cast<const float4*>(boxes)[bq];
            const float qav = angle[bq];
            float4 r;
            r.x = cost_fn(prob, qbv, qav, tb0, ta0, tl0);
            r.y = cost_fn(prob, qbv, qav, tb1, ta1, tl1);
            r.z = cost_fn(prob, qbv, qav, tb2, ta2, tl2);
            r.w = cost_fn(prob, qbv, qav, tb3, ta3, tl3);
            reinterpret_cast<float4*>(out + (size_t)bq * TT)[tid] = r;
        }
        return;
    }

    // ---------------- solver path (degenerate-LSA, exact) ----------------
    __builtin_amdgcn_s_setprio(3);
    const int b = blockIdx.x;
    const int lane = tid & 63;
    const int wid = tid >> 6;

    for (int j = tid; j <= MCOLS; j += 256) p_col[j] = 0;
    if (tid < NT) {
        s_ta[tid] = tangle[b * NT + tid];
        s_tb[tid] = reinterpret_cast<const float4*>(tboxes)[b * NT + tid];
    }

    // Owned columns j = tid*4 + c + 1 (c = 0..3), packed as pairs {0,1},{2,3}.
    v2f QX[2], QY[2], QZ[2], QW[2], QA2[2], BASE2[2];
    {
        const float4 lg4 = reinterpret_cast<const float4*>(logits + b * NQ)[tid];
        const float4 an4 = reinterpret_cast<const float4*>(angle + b * NQ)[tid];
        const float4* bb = reinterpret_cast<const float4*>(boxes + (size_t)b * NQ * 4);
        const float4 b0 = bb[tid * 4 + 0], b1 = bb[tid * 4 + 1];
        const float4 b2 = bb[tid * 4 + 2], b3 = bb[tid * 4 + 3];
        QX[0] = v2f{b0.x, b1.x}; QX[1] = v2f{b2.x, b3.x};
        QY[0] = v2f{b0.y, b1.y}; QY[1] = v2f{b2.y, b3.y};
        QZ[0] = v2f{b0.z, b1.z}; QZ[1] = v2f{b2.z, b3.z};
        QW[0] = v2f{b0.w, b1.w}; QW[1] = v2f{b2.w, b3.w};
        QA2[0] = v2f{an4.x, an4.y}; QA2[1] = v2f{an4.z, an4.w};
        // tgt_labels === 1.0 => ref's 2*cl == -2*sigmoid exactly (validated r5)
        BASE2[0] = v2f{2.0f * (-sigmoidf_(lg4.x)), 2.0f * (-sigmoidf_(lg4.y))};
        BASE2[1] = v2f{2.0f * (-sigmoidf_(lg4.z)), 2.0f * (-sigmoidf_(lg4.w))};
    }
    double v_reg[4] = {0.0, 0.0, 0.0, 0.0};   // exact column duals
    double veval[4] = {0.0, 0.0, 0.0, 0.0};   // == v_reg, or -inf while used
    double u_reg[4] = {0.0, 0.0, 0.0, 0.0};   // u[p[j]] accum while used
    int asn = 0;                              // assigned-mask of owned cols
    const double NINF = -__builtin_inf();
    __syncthreads();

    int par = 0;
    for (int i = 1; i <= NT; ++i) {
        int used = 0;
        double u_i_acc = 0.0;                 // u[i] accum (virtual col 0)
        double u_i0 = 0.0;                    // fresh row: u[i] == 0
        float cta = s_ta[i - 1];
        float4 ctb = s_tb[i - 1];
        int j0 = 0;
        int jfinal = 0;

        for (int guard = 0; guard <= MCOLS; ++guard) {
            // mark j0 used (owner); u_reg starts from that row's entry u
            if (j0) {
                const int jj = j0 - 1;
                #pragma unroll
                for (int c = 0; c < 4; ++c)
                    if (jj == tid * 4 + c) {
                        used |= (1 << c);
                        u_reg[c] = u_i0;
                        veval[c] = NINF;      // (Cf-u)-(-inf) = +inf => masked
                    }
            }
            // eval owned columns, packed f32 (exact per-element IEEE order:
            // ((base+|da|) + 5*cb) -> f64: (-u), (-v))
            double cur[4];
            {
#pragma clang fp contract(off)
                const v2f tbx = {ctb.x, ctb.x}, tby = {ctb.y, ctb.y};
                const v2f tbz = {ctb.z, ctb.z}, tbw = {ctb.w, ctb.w};
                const v2f taa = {cta, cta};
                #pragma unroll
                for (int p = 0; p < 2; ++p) {
                    const v2f dx = QX[p] - tbx;
                    const v2f dy = QY[p] - tby;
                    const v2f dz = QZ[p] - tbz;
                    const v2f dw = QW[p] - tbw;
                    const v2f da = QA2[p] - taa;
                    const v2f adx = __builtin_elementwise_max(dx, -dx);
                    const v2f ady = __builtin_elementwise_max(dy, -dy);
                    const v2f adz = __builtin_elementwise_max(dz, -dz);
                    const v2f adw = __builtin_elementwise_max(dw, -dw);
                    const v2f ada = __builtin_elementwise_max(da, -da);
                    const v2f s01 = adx + ady;
                    const v2f s012 = s01 + adz;
                    const v2f cbv = s012 + adw;
                    const v2f t0v = BASE2[p] + ada;
                    const v2f t1v = cbv * 5.0f;
                    const v2f Cf = t0v + t1v;
                    cur[2 * p + 0] = ((double)Cf.x - u_i0) - veval[2 * p + 0];
                    cur[2 * p + 1] = ((double)Cf.y - u_i0) - veval[2 * p + 1];
                }
            }
            // per-thread argmin, lowest c on ties; packed idx = (col<<1)|asn
            const int base2i = (tid * 4 + 1) << 1;
            double b01 = cur[0]; int k01 = base2i | (asn & 1);
            if (cur[1] < b01) { b01 = cur[1]; k01 = (base2i + 2) | ((asn >> 1) & 1); }
            double b23 = cur[2]; int k23 = (base2i + 4) | ((asn >> 2) & 1);
            if (cur[3] < b23) { b23 = cur[3]; k23 = (base2i + 6) | ((asn >> 3) & 1); }
            double bval = b01; int bidx = k01;
            if (b23 < bval) { bval = b23; bidx = k23; }
            // wave value-min via DPP fmin (validated rounds 3-6)
            double mval = bval;
            DPP_FMIN(0x111, 0xF);   // row_shr:1
            DPP_FMIN(0x112, 0xF);   // row_shr:2
            DPP_FMIN(0x114, 0xF);   // row_shr:4
            DPP_FMIN(0x118, 0xF);   // row_shr:8
            DPP_FMIN(0x142, 0xA);   // row_bcast:15 -> rows 1,3
            DPP_FMIN(0x143, 0xC);   // row_bcast:31 -> rows 2,3
            // broadcast wave min; extract first-index argmin via ballot
            DU rv; rv.d = mval;
            const int mlo = __builtin_amdgcn_readlane(rv.i.x, 63);
            const int mhi = __builtin_amdgcn_readlane(rv.i.y, 63);
            DU wm; wm.i.x = mlo; wm.i.y = mhi;
            const unsigned long long eqm = __ballot(bval == wm.d);
            const int lanewin = __builtin_ctzll(eqm);
            const int wcol2 = __builtin_amdgcn_readlane(bidx, lanewin);
            if (lane == 0) s_comb[par][wid] = make_int4(mlo, mhi, wcol2, 0);
            __syncthreads();
            const int4 q0v = s_comb[par][0];
            const int4 q1v = s_comb[par][1];
            const int4 q2v = s_comb[par][2];
            const int4 q3v = s_comb[par][3];
            par ^= 1;
            // cross-wave lex-min: wave order == col order, '<' keeps low cols
            DU e0, e1, e2, e3;
            e0.i = make_int2(q0v.x, q0v.y); e1.i = make_int2(q1v.x, q1v.y);
            e2.i = make_int2(q2v.x, q2v.y); e3.i = make_int2(q3v.x, q3v.y);
            double dA = e0.d; int kA = q0v.z;
            if (e1.d < dA) { dA = e1.d; kA = q1v.z; }
            double dB = e2.d; int kB = q2v.z;
            if (e3.d < dB) { dB = e3.d; kB = q3v.z; }
            double delta = dA; int pk = kA;
            if (dB < delta) { delta = dB; pk = kB; }
            // dual updates (register-resident, exact per-iteration order)
            u_i_acc += delta;
            #pragma unroll
            for (int c = 0; c < 4; ++c)
                if ((used >> c) & 1) { u_reg[c] += delta; v_reg[c] -= delta; }
            const int j1 = pk >> 1;
            // unconditional prefetch of next row's data (unused if we break)
            const double u1 = u_col[j1];
            const float t1 = ta_col[j1];
            const float4 b1 = tb_col[j1];
            if (!(pk & 1)) { jfinal = j1; break; }   // unassigned -> row done
            j0 = j1; u_i0 = u1; cta = t1; ctb = b1;
        }
        // row end: disjoint writes, ordered by the next iteration's barrier;
        // restore veval for cols used this row (they're assigned now).
        #pragma unroll
        for (int c = 0; c < 4; ++c)
            if ((used >> c) & 1) {
                u_col[tid * 4 + c + 1] = u_reg[c];
                veval[c] = v_reg[c];
            }
        if (tid == 0) {
            p_col[jfinal] = i;
            u_col[jfinal] = u_i_acc;
            ta_col[jfinal] = s_ta[i - 1];
            tb_col[jfinal] = s_tb[i - 1];
        }
        const int jf = jfinal - 1;
        #pragma unroll
        for (int c = 0; c < 4; ++c)
            if (jf == tid * 4 + c) asn |= (1 << c);
    }
    __syncthreads();

    // Emit matches in ascending column (=query) order: ballot compaction.
    int pl[4];
    #pragma unroll
    for (int c = 0; c < 4; ++c) pl[c] = p_col[tid * 4 + c + 1];
    const unsigned long long lt = (1ull << lane) - 1ull;
    int rank = 0, wtot = 0;
    #pragma unroll
    for (int c = 0; c < 4; ++c) {
        const unsigned long long bc = __ballot(pl[c] > 0);
        rank += __popcll(bc & lt);
        wtot += __popcll(bc);
    }
    if (lane == 0) s_wsum[wid] = wtot;
    __syncthreads();
    int bsum = 0;
    #pragma unroll
    for (int w = 0; w < 4; ++w)
        if (w < wid) bsum += s_wsum[w];
    int off = bsum + rank;
    float* rout = out + (size_t)CM_ELEMS + b * NT;
    float* cout = out + (size_t)CM_ELEMS + TT + b * NT;
    #pragma unroll
    for (int c = 0; c < 4; ++c) {
        if (pl[c] > 0) {
            rout[off] = (float)(tid * 4 + c);     // query index (row_idx)
            cout[off] = (float)(pl[c] - 1);       // target index (col_idx)
            ++off;
        }
    }
}

extern "C" void kernel_launch(void* const* d_in, const int* in_sizes, int n_in,
                              void* d_out, int out_size, void* d_ws, size_t ws_size,
                              hipStream_t stream) {
    const float* logits  = (const float*)d_in[0];
    const float* boxes   = (const float*)d_in[1];
    const float* angle   = (const float*)d_in[2];
    const float* tboxes  = (const float*)d_in[3];
    const float* tangle  = (const float*)d_in[4];
    const float* tlabels = (const float*)d_in[5];
    float* out = (float*)d_out;

    hipLaunchKernelGGL(fused_kernel, dim3(NSOLVE + NCOST), dim3(256), 0, stream,
                       logits, boxes, angle, tboxes, tangle, tlabels, out);
}

// Round 8
// 146.946 us; speedup vs baseline: 1.0146x; 1.0146x over previous
//
#include <hip/hip_runtime.h>
#include <math.h>

#define BS 8
#define NQ 1024
#define NT 128                 // targets per batch (solver rows)
#define MCOLS 1024             // solver columns = NQ (transposed problem)
#define TT 1024                // total targets = BS*NT
#define CM_ELEMS (BS * NQ * TT)
#define NSOLVE 8               // solver blocks (one per batch)
#define NCOST 248              // cost blocks; NSOLVE+NCOST = 256 = #CUs

__device__ __forceinline__ float sigmoidf_(float x) {
    return 1.0f / (1.0f + expf(-x));
}

// Full cost (cost path). Strict sequential order, contraction off.
// Validated bit-compatible with the JAX reference in rounds 2-7.
__device__ __forceinline__ float cost_fn(float prob, float4 qb, float qa,
                                         float4 tb, float ta, float tl) {
#pragma clang fp contract(off)
    float cl = -(prob * tl);
    float ca = fabsf(qa - ta);
    float s01 = fabsf(qb.x - tb.x) + fabsf(qb.y - tb.y);
    float s012 = s01 + fabsf(qb.z - tb.z);
    float cb = s012 + fabsf(qb.w - tb.w);
    return (2.0f * cl + ca) + 5.0f * cb;
}

union DU { double d; int2 i; };

#define DPP_FMIN(CTRL, RMASK)                                                  \
    do {                                                                       \
        DU cv_; cv_.d = mval;                                                  \
        int lo_ = __builtin_amdgcn_update_dpp(cv_.i.x, cv_.i.x, (CTRL), (RMASK), 0xF, false); \
        int hi_ = __builtin_amdgcn_update_dpp(cv_.i.y, cv_.i.y, (CTRL), (RMASK), 0xF, false); \
        DU ov_; ov_.i.x = lo_; ov_.i.y = hi_;                                  \
        mval = fmin(mval, ov_.d);                                              \
    } while (0)

// ---------------- Fused kernel --------------------------------------------
// blocks 0..7: solver (round-5 scalar eval + veval masking);
// blocks 8..255: cost matrix, grid-stride over 8192 queries.
// 256 blocks == 256 CUs -> bijective block->CU map.
__global__ void __launch_bounds__(256) fused_kernel(
    const float* __restrict__ logits, const float* __restrict__ boxes,
    const float* __restrict__ angle,  const float* __restrict__ tboxes,
    const float* __restrict__ tangle, const float* __restrict__ tlabels,
    float* __restrict__ out) {
    const int tid = threadIdx.x;

    __shared__ double u_col[MCOLS + 1];      // u of the row assigned to col j
    __shared__ float4 tb_col[MCOLS + 1];     // target box of that row
    __shared__ float  ta_col[MCOLS + 1];     // target angle of that row
    __shared__ int    p_col[MCOLS + 1];      // assigned row (0 = none)
    __shared__ float  s_ta[NT];
    __shared__ float4 s_tb[NT];
    __shared__ int4   s_comb[2][4];          // parity-buffered wave partials
    __shared__ int    s_wsum[4];

    if (blockIdx.x >= NSOLVE) {
        // ---------------- cost-matrix path ----------------
        const int t0 = tid * 4;
        const float4 tb0 = reinterpret_cast<const float4*>(tboxes)[t0 + 0];
        const float4 tb1 = reinterpret_cast<const float4*>(tboxes)[t0 + 1];
        const float4 tb2 = reinterpret_cast<const float4*>(tboxes)[t0 + 2];
        const float4 tb3 = reinterpret_cast<const float4*>(tboxes)[t0 + 3];
        const float ta0 = tangle[t0 + 0], ta1 = tangle[t0 + 1];
        const float ta2 = tangle[t0 + 2], ta3 = tangle[t0 + 3];
        const float tl0 = tlabels[t0 + 0], tl1 = tlabels[t0 + 1];
        const float tl2 = tlabels[t0 + 2], tl3 = tlabels[t0 + 3];

        for (int bq = blockIdx.x - NSOLVE; bq < BS * NQ; bq += NCOST) {
            const float prob = sigmoidf_(logits[bq]);
            const float4 qbv = reinterpret_cast<const float4*>(boxes)[bq];
            const float qav = angle[bq];
            float4 r;
            r.x = cost_fn(prob, qbv, qav, tb0, ta0, tl0);
            r.y = cost_fn(prob, qbv, qav, tb1, ta1, tl1);
            r.z = cost_fn(prob, qbv, qav, tb2, ta2, tl2);
            r.w = cost_fn(prob, qbv, qav, tb3, ta3, tl3);
            reinterpret_cast<float4*>(out + (size_t)bq * TT)[tid] = r;
        }
        return;
    }

    // ---------------- solver path (degenerate-LSA, exact) ----------------
    __builtin_amdgcn_s_setprio(3);
    const int b = blockIdx.x;
    const int lane = tid & 63;
    const int wid = tid >> 6;

    for (int j = tid; j <= MCOLS; j += 256) p_col[j] = 0;
    if (tid < NT) {
        s_ta[tid] = tangle[b * NT + tid];
        s_tb[tid] = reinterpret_cast<const float4*>(tboxes)[b * NT + tid];
    }

    // Owned columns j = tid*4 + c + 1 (c = 0..3). Round-5 scalar layout:
    // fabsf folds into VOP3 abs-modifiers of the consuming adds (free).
    float base[4], qa[4];
    float4 qb[4];
    {
        const float4 lg4 = reinterpret_cast<const float4*>(logits + b * NQ)[tid];
        const float4 an4 = reinterpret_cast<const float4*>(angle + b * NQ)[tid];
        const float4* bb = reinterpret_cast<const float4*>(boxes + (size_t)b * NQ * 4);
        const float lgs[4] = {lg4.x, lg4.y, lg4.z, lg4.w};
        const float ans[4] = {an4.x, an4.y, an4.z, an4.w};
        #pragma unroll
        for (int c = 0; c < 4; ++c) {
            base[c] = 2.0f * (-sigmoidf_(lgs[c]));   // == ref's 2*cl (tl==1)
            qa[c] = ans[c];
            qb[c] = bb[tid * 4 + c];
        }
    }
    double v_reg[4] = {0.0, 0.0, 0.0, 0.0};   // exact column duals
    double veval[4] = {0.0, 0.0, 0.0, 0.0};   // == v_reg, or -inf while used
    double u_reg[4] = {0.0, 0.0, 0.0, 0.0};   // u[p[j]] accum while used
    int asn = 0;                              // assigned-mask of owned cols
    const double NINF = -__builtin_inf();
    __syncthreads();

    int par = 0;
    for (int i = 1; i <= NT; ++i) {
        int used = 0;
        double u_i_acc = 0.0;                 // u[i] accum (virtual col 0)
        double u_i0 = 0.0;                    // fresh row: u[i] == 0
        float cta = s_ta[i - 1];
        float4 ctb = s_tb[i - 1];
        int j0 = 0;
        int jfinal = 0;

        for (int guard = 0; guard <= MCOLS; ++guard) {
            // mark j0 used (owner); u_reg starts from that row's entry u
            if (j0) {
                const int jj = j0 - 1;
                #pragma unroll
                for (int c = 0; c < 4; ++c)
                    if (jj == tid * 4 + c) {
                        used |= (1 << c);
                        u_reg[c] = u_i0;
                        veval[c] = NINF;      // (Cf-u)-(-inf) = +inf => masked
                    }
            }
            // eval owned columns, scalar f32 (exact ref order:
            // ((base+ca) + 5*cb) -> f64: (-u), (-veval))
            double cur[4];
            {
#pragma clang fp contract(off)
                #pragma unroll
                for (int c = 0; c < 4; ++c) {
                    const float ca = fabsf(qa[c] - cta);
                    const float s01 = fabsf(qb[c].x - ctb.x) + fabsf(qb[c].y - ctb.y);
                    const float s012 = s01 + fabsf(qb[c].z - ctb.z);
                    const float cb = s012 + fabsf(qb[c].w - ctb.w);
                    const float Cf = (base[c] + ca) + 5.0f * cb;
                    cur[c] = ((double)Cf - u_i0) - veval[c];
                }
            }
            // per-thread argmin, lowest c on ties; packed idx = (col<<1)|asn
            const int base2i = (tid * 4 + 1) << 1;
            double b01 = cur[0]; int k01 = base2i | (asn & 1);
            if (cur[1] < b01) { b01 = cur[1]; k01 = (base2i + 2) | ((asn >> 1) & 1); }
            double b23 = cur[2]; int k23 = (base2i + 4) | ((asn >> 2) & 1);
            if (cur[3] < b23) { b23 = cur[3]; k23 = (base2i + 6) | ((asn >> 3) & 1); }
            double bval = b01; int bidx = k01;
            if (b23 < bval) { bval = b23; bidx = k23; }
            // wave value-min via DPP fmin (validated rounds 3-7)
            double mval = bval;
            DPP_FMIN(0x111, 0xF);   // row_shr:1
            DPP_FMIN(0x112, 0xF);   // row_shr:2
            DPP_FMIN(0x114, 0xF);   // row_shr:4
            DPP_FMIN(0x118, 0xF);   // row_shr:8
            DPP_FMIN(0x142, 0xA);   // row_bcast:15 -> rows 1,3
            DPP_FMIN(0x143, 0xC);   // row_bcast:31 -> rows 2,3
            // broadcast wave min; extract first-index argmin via ballot
            DU rv; rv.d = mval;
            const int mlo = __builtin_amdgcn_readlane(rv.i.x, 63);
            const int mhi = __builtin_amdgcn_readlane(rv.i.y, 63);
            DU wm; wm.i.x = mlo; wm.i.y = mhi;
            const unsigned long long eqm = __ballot(bval == wm.d);
            const int lanewin = __builtin_ctzll(eqm);
            const int wcol2 = __builtin_amdgcn_readlane(bidx, lanewin);
            if (lane == 0) s_comb[par][wid] = make_int4(mlo, mhi, wcol2, 0);
            __syncthreads();
            const int4 q0v = s_comb[par][0];
            const int4 q1v = s_comb[par][1];
            const int4 q2v = s_comb[par][2];
            const int4 q3v = s_comb[par][3];
            par ^= 1;
            // cross-wave lex-min: wave order == col order, '<' keeps low cols
            DU e0, e1, e2, e3;
            e0.i = make_int2(q0v.x, q0v.y); e1.i = make_int2(q1v.x, q1v.y);
            e2.i = make_int2(q2v.x, q2v.y); e3.i = make_int2(q3v.x, q3v.y);
            double dA = e0.d; int kA = q0v.z;
            if (e1.d < dA) { dA = e1.d; kA = q1v.z; }
            double dB = e2.d; int kB = q2v.z;
            if (e3.d < dB) { dB = e3.d; kB = q3v.z; }
            double delta = dA; int pk = kA;
            if (dB < delta) { delta = dB; pk = kB; }
            // dual updates (register-resident, exact per-iteration order)
            u_i_acc += delta;
            #pragma unroll
            for (int c = 0; c < 4; ++c)
                if ((used >> c) & 1) { u_reg[c] += delta; v_reg[c] -= delta; }
            const int j1 = pk >> 1;
            // unconditional prefetch of next row's data (unused if we break)
            const double u1 = u_col[j1];
            const float t1 = ta_col[j1];
            const float4 b1 = tb_col[j1];
            if (!(pk & 1)) { jfinal = j1; break; }   // unassigned -> row done
            j0 = j1; u_i0 = u1; cta = t1; ctb = b1;
        }
        // row end: disjoint writes, ordered by the next iteration's barrier;
        // restore veval for cols used this row (they're assigned now).
        #pragma unroll
        for (int c = 0; c < 4; ++c)
            if ((used >> c) & 1) {
                u_col[tid * 4 + c + 1] = u_reg[c];
                veval[c] = v_reg[c];
            }
        if (tid == 0) {
            p_col[jfinal] = i;
            u_col[jfinal] = u_i_acc;
            ta_col[jfinal] = s_ta[i - 1];
            tb_col[jfinal] = s_tb[i - 1];
        }
        const int jf = jfinal - 1;
        #pragma unroll
        for (int c = 0; c < 4; ++c)
            if (jf == tid * 4 + c) asn |= (1 << c);
    }
    __syncthreads();

    // Emit matches in ascending column (=query) order: ballot compaction.
    int pl[4];
    #pragma unroll
    for (int c = 0; c < 4; ++c) pl[c] = p_col[tid * 4 + c + 1];
    const unsigned long long lt = (1ull << lane) - 1ull;
    int rank = 0, wtot = 0;
    #pragma unroll
    for (int c = 0; c < 4; ++c) {
        const unsigned long long bc = __ballot(pl[c] > 0);
        rank += __popcll(bc & lt);
        wtot += __popcll(bc);
    }
    if (lane == 0) s_wsum[wid] = wtot;
    __syncthreads();
    int bsum = 0;
    #pragma unroll
    for (int w = 0; w < 4; ++w)
        if (w < wid) bsum += s_wsum[w];
    int off = bsum + rank;
    float* rout = out + (size_t)CM_ELEMS + b * NT;
    float* cout = out + (size_t)CM_ELEMS + TT + b * NT;
    #pragma unroll
    for (int c = 0; c < 4; ++c) {
        if (pl[c] > 0) {
            rout[off] = (float)(tid * 4 + c);     // query index (row_idx)
            cout[off] = (float)(pl[c] - 1);       // target index (col_idx)
            ++off;
        }
    }
}

extern "C" void kernel_launch(void* const* d_in, const int* in_sizes, int n_in,
                              void* d_out, int out_size, void* d_ws, size_t ws_size,
                              hipStream_t stream) {
    const float* logits  = (const float*)d_in[0];
    const float* boxes   = (const float*)d_in[1];
    const float* angle   = (const float*)d_in[2];
    const float* tboxes  = (const float*)d_in[3];
    const float* tangle  = (const float*)d_in[4];
    const float* tlabels = (const float*)d_in[5];
    float* out = (float*)d_out;

    hipLaunchKernelGGL(fused_kernel, dim3(NSOLVE + NCOST), dim3(256), 0, stream,
                       logits, boxes, angle, tboxes, tangle, tlabels, out);
}